// Round 13
// baseline (277.822 us; speedup 1.0000x reference)
//
#include <hip/hip_runtime.h>

#define H_ 32
#define E_ 32
#define C_ 1024
#define L_ 1024
#define N_ 4
#define M_ 4096      // N_*L_
#define NH_ 128      // N_*H_
#define D_ 257
#define DPAD 272     // demb padded rows (zeros beyond 256)
#define QDS 256      // QD row stride in LDS (col 256 lives in a register)
#define TEMP_ 0.17677669529663687f
#define QSCALE_ (TEMP_ * 1.4426950408889634f)   // temp * log2(e), folded into q & KD

typedef unsigned short u16;
typedef __attribute__((ext_vector_type(8))) short short8;
typedef __attribute__((ext_vector_type(4))) float f32x4;
typedef __attribute__((ext_vector_type(4))) unsigned short u16x4;

__device__ __forceinline__ u16 f2bf(float f) {
  union { float f; unsigned u; } v; v.f = f;
  unsigned r = v.u + 0x7fffu + ((v.u >> 16) & 1u);
  return (u16)(r >> 16);
}
__device__ __forceinline__ float bf2f(u16 h) {
  union { unsigned u; float f; } v; v.u = ((unsigned)h) << 16;
  return v.f;
}
__device__ __forceinline__ f32x4 mfma16(short8 a, short8 b, f32x4 c) {
  return __builtin_amdgcn_mfma_f32_16x16x32_bf16(a, b, c, 0, 0, 0);
}
__device__ __forceinline__ float ex2(float x) {
#if __has_builtin(__builtin_amdgcn_exp2f)
  return __builtin_amdgcn_exp2f(x);
#else
  float r;
  asm("v_exp_f32 %0, %1\n\ts_nop 1" : "=v"(r) : "v"(x));
  return r;
#endif
}
// async global->LDS, 16B per lane; lds base must be wave-uniform
__device__ __forceinline__ void gld16(const u16* g, u16* l) {
  __builtin_amdgcn_global_load_lds(
      (const __attribute__((address_space(1))) unsigned int*)g,
      (__attribute__((address_space(3))) unsigned int*)l, 16, 0, 0);
}

// ---- prep (fused): x->bf16, dist_emb->bf16 (padded), bias pack, 5 W^T ----
// b in [0,4096): cvt x | [4096,4130): demb/bias | [4130,9250): transposes
__global__ __launch_bounds__(256) void prep_kernel(
    const float* __restrict__ x, const float* __restrict__ demb,
    const float* __restrict__ bq, const float* __restrict__ bk,
    const float* __restrict__ bv, const float* __restrict__ Wq,
    const float* __restrict__ Wk, const float* __restrict__ Wv,
    const float* __restrict__ W1, const float* __restrict__ W2,
    u16* __restrict__ xb, u16* __restrict__ demb_b,
    float* __restrict__ bqkv, u16* __restrict__ wt_base) {
  const int b = blockIdx.x, tid = threadIdx.x;
  if (b < 4096) {
    int i = b * 256 + tid;
    f32x4 v = reinterpret_cast<const f32x4*>(x)[i];
    u16x4 o2;
    o2[0] = f2bf(v[0]); o2[1] = f2bf(v[1]); o2[2] = f2bf(v[2]); o2[3] = f2bf(v[3]);
    reinterpret_cast<u16x4*>(xb)[i] = o2;
  } else if (b < 4130) {
    int i = (b - 4096) * 256 + tid;
    if (i < DPAD * E_) demb_b[i] = (i < D_ * E_) ? f2bf(demb[i]) : (u16)0;
    if (i < C_) { bqkv[i] = bq[i]; bqkv[C_ + i] = bk[i]; bqkv[2 * C_ + i] = bv[i]; }
  } else {
    __shared__ float tile[32][33];
    const int t = b - 4130;
    const int z = t >> 10, rem = t & 1023;
    const int j0 = (rem & 31) * 32, c0 = (rem >> 5) * 32;
    const float* in = (z == 0) ? Wq : (z == 1) ? Wk : (z == 2) ? Wv : (z == 3) ? W1 : W2;
    u16* out = wt_base + (size_t)z * C_ * C_;
    const int tx = tid & 31, ty = tid >> 5;
#pragma unroll
    for (int i = 0; i < 4; ++i) {
      int cy = ty + i * 8;
      tile[cy][tx] = in[(size_t)(c0 + cy) * C_ + j0 + tx];
    }
    __syncthreads();
#pragma unroll
    for (int i = 0; i < 4; ++i) {
      int jy = ty + i * 8;
      out[(size_t)(j0 + jy) * C_ + c0 + tx] = f2bf(tile[tx][jy]);
    }
  }
}

// ---- GEMM 128x128 (qkv): XCD-swizzled bid (grid 768 = 8 x 96) ----
template <int EPI>
__global__ __launch_bounds__(256) void gemm128_kernel(
    const u16* __restrict__ A, const u16* __restrict__ Bt, int K,
    const float* __restrict__ bias,
    u16* __restrict__ out0, u16* __restrict__ out1, u16* __restrict__ out2) {
  __shared__ u16 As[128 * 64];
  __shared__ u16 Bs[128 * 64];
  const int bid = (blockIdx.x & 7) * 96 + (blockIdx.x >> 3);   // XCD-contiguous
  const int m0 = (bid & 31) << 7;
  const int n0 = (bid >> 5) << 7;
  const int tid = threadIdx.x;
  const int w = tid >> 6, lane = tid & 63, lhi = lane >> 4, llo = lane & 15;
  const int wr = w >> 1, wc = w & 1;
  const int w4 = w << 2;
  const int srow = lane >> 3, scol = (lane & 7) << 3;
  f32x4 acc[4][4] = {};
  for (int k0 = 0; k0 < K; k0 += 64) {
#pragma unroll
    for (int j = 0; j < 4; ++j) {
      const int seg = w4 + j;
      const int row = (seg << 3) + srow;
      gld16(&A[(size_t)(m0 + row) * K + k0 + scol], &As[seg << 9]);
      gld16(&Bt[(size_t)(n0 + row) * K + k0 + scol], &Bs[seg << 9]);
    }
    __syncthreads();
#pragma unroll
    for (int kk = 0; kk < 2; ++kk) {
      const int ko = (kk << 5) + lhi * 8;
      short8 af[4], bf[4];
#pragma unroll
      for (int mi = 0; mi < 4; ++mi)
        af[mi] = *reinterpret_cast<const short8*>(&As[(wr * 64 + mi * 16 + llo) * 64 + ko]);
#pragma unroll
      for (int ni = 0; ni < 4; ++ni)
        bf[ni] = *reinterpret_cast<const short8*>(&Bs[(wc * 64 + ni * 16 + llo) * 64 + ko]);
#pragma unroll
      for (int mi = 0; mi < 4; ++mi)
#pragma unroll
        for (int ni = 0; ni < 4; ++ni)
          acc[mi][ni] = mfma16(af[mi], bf[ni], acc[mi][ni]);
    }
    __syncthreads();
  }
#pragma unroll
  for (int mi = 0; mi < 4; ++mi)
#pragma unroll
    for (int ni = 0; ni < 4; ++ni)
#pragma unroll
      for (int r = 0; r < 4; ++r) {
        int row = m0 + wr * 64 + mi * 16 + lhi * 4 + r;
        int col = n0 + wc * 64 + ni * 16 + llo;
        float v = acc[mi][ni][r] + bias[col];
        if constexpr (EPI == 0) {
          int which = col >> 10, jj = col & 1023, h = jj >> 5, e2 = jj & 31;
          int n = row >> 10, l = row & 1023;
          int nh = (n << 5) | h;
          if (which == 0) v *= QSCALE_;   // fold temp*log2e into q
          u16 bvv = f2bf(v);
          if (which == 0)      out0[((size_t)((nh << 10) | l)) * 32 + e2] = bvv;
          else if (which == 1) out1[((size_t)((nh << 10) | l)) * 32 + e2] = bvv;
          else                 out2[(((size_t)(nh * 32 + e2)) << 10) | l] = bvv;
        } else if constexpr (EPI == 1) {
          out0[(size_t)row * C_ + col] = f2bf(fmaxf(v, 0.f));
        } else {
          out0[(size_t)row * C_ + col] = f2bf(v);
        }
      }
}

// ---- GEMM 64x128 (MLP): XCD-swizzled bid (grid 512 = 8 x 64) ----
template <int EPI>
__global__ __launch_bounds__(256, 4) void gemm64_kernel(
    const u16* __restrict__ A, const u16* __restrict__ Bt, int K,
    const float* __restrict__ bias, u16* __restrict__ out0) {
  __shared__ u16 As[64 * 64];     // 8192 B
  __shared__ u16 Bs[128 * 64];    // 16384 B
  const int bid = (blockIdx.x & 7) * 64 + (blockIdx.x >> 3);   // XCD-contiguous
  const int m0 = (bid & 63) << 6;
  const int n0 = (bid >> 6) << 7;
  const int tid = threadIdx.x;
  const int w = tid >> 6, lane = tid & 63, lhi = lane >> 4, llo = lane & 15;
  const int wr = w >> 1, wc = w & 1;   // wr: 32-row half, wc: 64-col half
  const int srow = lane >> 3, scol = (lane & 7) << 3;
  f32x4 acc[2][4] = {};
  for (int k0 = 0; k0 < K; k0 += 64) {
#pragma unroll
    for (int j = 0; j < 2; ++j) {       // A: 8 segs of 8 rows
      const int seg = w * 2 + j;
      const int row = (seg << 3) + srow;
      gld16(&A[(size_t)(m0 + row) * K + k0 + scol], &As[seg << 9]);
    }
#pragma unroll
    for (int j = 0; j < 4; ++j) {       // B: 16 segs of 8 rows
      const int seg = w * 4 + j;
      const int row = (seg << 3) + srow;
      gld16(&Bt[(size_t)(n0 + row) * K + k0 + scol], &Bs[seg << 9]);
    }
    __syncthreads();
#pragma unroll
    for (int kk = 0; kk < 2; ++kk) {
      const int ko = (kk << 5) + lhi * 8;
      short8 af[2], bf[4];
#pragma unroll
      for (int mi = 0; mi < 2; ++mi)
        af[mi] = *reinterpret_cast<const short8*>(&As[(wr * 32 + mi * 16 + llo) * 64 + ko]);
#pragma unroll
      for (int ni = 0; ni < 4; ++ni)
        bf[ni] = *reinterpret_cast<const short8*>(&Bs[(wc * 64 + ni * 16 + llo) * 64 + ko]);
#pragma unroll
      for (int mi = 0; mi < 2; ++mi)
#pragma unroll
        for (int ni = 0; ni < 4; ++ni)
          acc[mi][ni] = mfma16(af[mi], bf[ni], acc[mi][ni]);
    }
    __syncthreads();
  }
#pragma unroll
  for (int mi = 0; mi < 2; ++mi)
#pragma unroll
    for (int ni = 0; ni < 4; ++ni)
#pragma unroll
      for (int r = 0; r < 4; ++r) {
        int row = m0 + wr * 32 + mi * 16 + lhi * 4 + r;
        int col = n0 + wc * 64 + ni * 16 + llo;
        float v = acc[mi][ni][r] + bias[col];
        if constexpr (EPI == 1) out0[(size_t)row * C_ + col] = f2bf(fmaxf(v, 0.f));
        else                    out0[(size_t)row * C_ + col] = f2bf(v);
      }
}

// ---- KD: dst[m, d] = QSCALE * sum_e k[m, e] * demb[d, e]; aux clamp vecs ----
__global__ __launch_bounds__(256) void qdkd_kernel(
    const u16* __restrict__ src, const u16* __restrict__ demb,
    u16* __restrict__ dst, u16* __restrict__ aux0, u16* __restrict__ aux256) {
  const int wt = blockIdx.x * 4 + (threadIdx.x >> 6);
  const int lane = threadIdx.x & 63, lhi = lane >> 4, llo = lane & 15;
  const int m0 = wt << 4;
  short8 a = *reinterpret_cast<const short8*>(&src[(size_t)(m0 + llo) * E_ + lhi * 8]);
#pragma unroll
  for (int ct = 0; ct < 17; ++ct) {
    int d = ct * 16 + llo;
    short8 b = *reinterpret_cast<const short8*>(&demb[d * E_ + lhi * 8]);
    f32x4 c = {};
    c = mfma16(a, b, c);
    if (d < D_) {
#pragma unroll
      for (int r = 0; r < 4; ++r) {
        u16 val = f2bf(c[r] * QSCALE_);
        dst[(size_t)(m0 + lhi * 4 + r) * D_ + d] = val;
        if (d == 0)   aux0[m0 + lhi * 4 + r] = val;
        if (d == 256) aux256[m0 + lhi * 4 + r] = val;
      }
    }
  }
}

// ---- attention (R12 form, 127us floor): x2-unrolled mfma(K,Q) streaming ----
__global__ __launch_bounds__(256, 4) void attn_kernel(
    const u16* __restrict__ qw, const u16* __restrict__ kw,
    const u16* __restrict__ vT, const u16* __restrict__ dembp,
    const u16* __restrict__ KDg, const u16* __restrict__ kd0a,
    const u16* __restrict__ kd256a, u16* __restrict__ tb) {
  __shared__ u16 QDs[64 * QDS];   // 32768 B, wave-local
  __shared__ u16 Pbuf[4 * 1024];  // 8192 B: per-wave 2KB = two 1KB P buffers
  const int bid = blockIdx.x;
  const int nh = bid & (NH_ - 1);     // XCD-friendly
  const int l0 = (bid >> 7) << 6;
  const int tid = threadIdx.x;
  const int w = tid >> 6, lane = tid & 63, lhi = lane >> 4, llo = lane & 15;
  const int lw0 = l0 + (w << 4);
  const int lg = lw0 + llo;
  const int lrow = (w << 4) + llo;    // this lane's q-row within QDs

  const u16* qb  = qw + (size_t)nh * (L_ * E_);
  const u16* kb  = kw + (size_t)nh * (L_ * E_);
  const u16* vb  = vT + (size_t)nh * (E_ * L_);
  const u16* kdg = KDg + (size_t)nh * ((size_t)L_ * D_);
  const u16* k0g = kd0a + (size_t)nh * L_;
  const u16* k2g = kd256a + (size_t)nh * L_;

  const short8 qA = *(const short8*)&qb[(size_t)lg * E_ + lhi * 8];
  const int qr4 = (w << 4) + (lhi << 2);

  char* Pw = reinterpret_cast<char*>(&Pbuf[w * 1024]);   // 2KB region

  // in-kernel QD: rows for this wave only; cols 0..255 in LDS
#pragma unroll
  for (int dt = 0; dt < 16; ++dt) {
    short8 db = *(const short8*)&dembp[(dt * 16 + llo) * E_ + lhi * 8];
    f32x4 qd = {};
    qd = mfma16(qA, db, qd);
#pragma unroll
    for (int r = 0; r < 4; ++r)
      QDs[(qr4 + r) * QDS + dt * 16 + llo] = f2bf(qd[r]);
  }
  // col 256 -> register, via one-time per-wave stash in Pw (overwritten later)
  float qd256;
  {
    short8 db = *(const short8*)&dembp[(size_t)(256 + llo) * E_ + lhi * 8];
    f32x4 qd = {};
    qd = mfma16(qA, db, qd);
    u16* stash = reinterpret_cast<u16*>(Pw);
    if (llo == 0) {
#pragma unroll
      for (int r = 0; r < 4; ++r) stash[(lhi << 2) + r] = f2bf(qd[r]);
    }
    qd256 = bf2f(stash[llo]);   // same-wave LDS, lgkm-ordered
  }
  const float qd0 = bf2f(QDs[lrow * QDS + 0]);

  f32x4 o0 = {}, o1 = {};
  float lacc = 0.f;

#define ASM_SCORE(S0, ST0, ST1, P)                                             \
  {                                                                            \
    const int s0_ = (S0);                                                      \
    const bool far_hi = (lw0 - (s0_ + 31)) >= 128;                             \
    const bool far_lo = (s0_ - (lw0 + 15)) >= 128;                             \
    if (far_hi || far_lo) {                                                    \
      const float qdc = far_hi ? qd256 : qd0;                                  \
      const u16* kcg = far_hi ? k2g : k0g;                                     \
      u16x4 kc0 = *(const u16x4*)&kcg[s0_ + lhi * 4];                          \
      u16x4 kc1 = *(const u16x4*)&kcg[s0_ + 16 + lhi * 4];                     \
      _Pragma("unroll") for (int r = 0; r < 4; ++r) {                          \
        P[r]     = ex2(ST0[r] + qdc + bf2f(kc0[r]));                           \
        P[4 + r] = ex2(ST1[r] + qdc + bf2f(kc1[r]));                           \
      }                                                                        \
    } else {                                                                   \
      _Pragma("unroll") for (int i = 0; i < 2; ++i)                            \
        _Pragma("unroll") for (int r = 0; r < 4; ++r) {                        \
          const int scol = s0_ + i * 16 + lhi * 4 + r;                         \
          int d = lg - scol;                                                   \
          d = (d < -128 ? -128 : (d > 128 ? 128 : d)) + 128;                   \
          int dc = d > 255 ? 255 : d;                                          \
          float qd = (d == 256) ? qd256 : bf2f(QDs[lrow * QDS + dc]);          \
          float kd = bf2f(kdg[(size_t)scol * D_ + d]);                         \
          P[i * 4 + r] = ex2((i ? ST1[r] : ST0[r]) + qd + kd);                 \
        }                                                                      \
    }                                                                          \
  }

#define PACKP(P, OFF)                                                          \
  _Pragma("unroll") for (int i = 0; i < 2; ++i)                                \
    _Pragma("unroll") for (int b = 0; b < 2; ++b) {                            \
      union { float f; unsigned u; } a0_, a1_;                                 \
      a0_.f = P[i * 4 + 2 * b]; a1_.f = P[i * 4 + 2 * b + 1];                  \
      unsigned wv_ = ((a0_.u + 0x8000u) >> 16) | ((a1_.u + 0x8000u) & 0xffff0000u); \
      int u_ = (i * 4 + lhi) ^ (llo & 6);                                      \
      *reinterpret_cast<unsigned*>(Pw + (OFF) + llo * 64 + u_ * 8 + b * 4) = wv_; \
    }

  for (int s0 = 0; s0 < L_; s0 += 64) {
    const int sb = s0 + 32;
    short8 kA0a = *(const short8*)&kb[(size_t)(s0 + llo) * E_ + lhi * 8];
    short8 kA1a = *(const short8*)&kb[(size_t)(s0 + 16 + llo) * E_ + lhi * 8];
    short8 kA0b = *(const short8*)&kb[(size_t)(sb + llo) * E_ + lhi * 8];
    short8 kA1b = *(const short8*)&kb[(size_t)(sb + 16 + llo) * E_ + lhi * 8];
    short8 vA0a = *(const short8*)&vb[(size_t)llo * L_ + s0 + lhi * 8];
    short8 vA1a = *(const short8*)&vb[(size_t)(16 + llo) * L_ + s0 + lhi * 8];
    short8 vA0b = *(const short8*)&vb[(size_t)llo * L_ + sb + lhi * 8];
    short8 vA1b = *(const short8*)&vb[(size_t)(16 + llo) * L_ + sb + lhi * 8];

    f32x4 st0a = {}, st1a = {}, st0b = {}, st1b = {};
    st0a = mfma16(kA0a, qA, st0a);
    st1a = mfma16(kA1a, qA, st1a);
    st0b = mfma16(kA0b, qA, st0b);
    st1b = mfma16(kA1b, qA, st1b);

    float pa[8], pb[8];
    ASM_SCORE(s0, st0a, st1a, pa);
    ASM_SCORE(sb, st0b, st1b, pb);

    lacc += ((pa[0] + pa[1]) + (pa[2] + pa[3])) + ((pa[4] + pa[5]) + (pa[6] + pa[7]));
    lacc += ((pb[0] + pb[1]) + (pb[2] + pb[3])) + ((pb[4] + pb[5]) + (pb[6] + pb[7]));

    PACKP(pa, 0);
    PACKP(pb, 1024);

    short8 pBa = *reinterpret_cast<const short8*>(
        Pw + llo * 64 + (((lhi * 2) ^ (llo & 6)) * 8));
    short8 pBb = *reinterpret_cast<const short8*>(
        Pw + 1024 + llo * 64 + (((lhi * 2) ^ (llo & 6)) * 8));
    o0 = mfma16(vA0a, pBa, o0);
    o1 = mfma16(vA1a, pBa, o1);
    o0 = mfma16(vA0b, pBb, o0);
    o1 = mfma16(vA1b, pBb, o1);
  }
#undef ASM_SCORE
#undef PACKP

  // row sum across the 4 lanes sharing llo (lane, lane^16, lane^32, lane^48)
  float l2 = lacc + __shfl_xor(lacc, 16);
  float lt = l2 + __shfl_xor(l2, 32);
  const float inv = 1.0f / lt;

  const int n = nh >> 5, h = nh & 31;
  const size_t obase = (((size_t)((n << 10) | lg)) * 32 + h) * 32;
  u16x4 w0, w1;
#pragma unroll
  for (int r = 0; r < 4; ++r) {
    w0[r] = f2bf(o0[r] * inv);
    w1[r] = f2bf(o1[r] * inv);
  }
  *reinterpret_cast<u16x4*>(&tb[obase + lhi * 4]) = w0;        // e = lhi*4+r
  *reinterpret_cast<u16x4*>(&tb[obase + 16 + lhi * 4]) = w1;   // e = 16+lhi*4+r
}

// ---- AddNorm 1: h = LN(t + x) -> bf16 ----
__global__ __launch_bounds__(256) void ln1_kernel(
    const u16* __restrict__ tbuf, const float* __restrict__ x,
    const float* __restrict__ g, const float* __restrict__ b,
    u16* __restrict__ hb) {
  __shared__ float red[8];
  const int row = blockIdx.x, tid = threadIdx.x;
  const size_t base = (size_t)row * C_ + tid * 4;
  f32x4 xv = *reinterpret_cast<const f32x4*>(&x[base]);
  u16x4 tv = *reinterpret_cast<const u16x4*>(&tbuf[base]);
  float v[4]; float s1 = 0.f, s2 = 0.f;
#pragma unroll
  for (int i = 0; i < 4; ++i) {
    v[i] = xv[i] + bf2f(tv[i]);
    s1 += v[i]; s2 += v[i] * v[i];
  }
#pragma unroll
  for (int off = 32; off >= 1; off >>= 1) {
    s1 += __shfl_xor(s1, off); s2 += __shfl_xor(s2, off);
  }
  if ((tid & 63) == 0) { red[tid >> 6] = s1; red[4 + (tid >> 6)] = s2; }
  __syncthreads();
  float S1 = red[0] + red[1] + red[2] + red[3];
  float S2 = red[4] + red[5] + red[6] + red[7];
  float mu = S1 * (1.f / C_);
  float rs = rsqrtf(S2 * (1.f / C_) - mu * mu + 1e-5f);
#pragma unroll
  for (int i = 0; i < 4; ++i) {
    int c = tid * 4 + i;
    hb[base + i] = f2bf((v[i] - mu) * rs * g[c] + b[c]);
  }
}

// ---- AddNorm 2: out = LN(m + h) -> fp32, transposed (L, N, C) ----
__global__ __launch_bounds__(256) void ln2_kernel(
    const u16* __restrict__ mb, const u16* __restrict__ hb,
    const float* __restrict__ g, const float* __restrict__ b,
    float* __restrict__ out) {
  __shared__ float red[8];
  const int row = blockIdx.x, tid = threadIdx.x;
  const size_t base = (size_t)row * C_ + tid * 4;
  u16x4 mv = *reinterpret_cast<const u16x4*>(&mb[base]);
  u16x4 hv = *reinterpret_cast<const u16x4*>(&hb[base]);
  float v[4]; float s1 = 0.f, s2 = 0.f;
#pragma unroll
  for (int i = 0; i < 4; ++i) {
    v[i] = bf2f(mv[i]) + bf2f(hv[i]);
    s1 += v[i]; s2 += v[i] * v[i];
  }
#pragma unroll
  for (int off = 32; off >= 1; off >>= 1) {
    s1 += __shfl_xor(s1, off); s2 += __shfl_xor(s2, off);
  }
  if ((tid & 63) == 0) { red[tid >> 6] = s1; red[4 + (tid >> 6)] = s2; }
  __syncthreads();
  float S1 = red[0] + red[1] + red[2] + red[3];
  float S2 = red[4] + red[5] + red[6] + red[7];
  float mu = S1 * (1.f / C_);
  float rs = rsqrtf(S2 * (1.f / C_) - mu * mu + 1e-5f);
  const int n = row >> 10, l = row & 1023;
  const size_t ob = (size_t)(l * N_ + n) * C_ + tid * 4;
#pragma unroll
  for (int i = 0; i < 4; ++i) {
    int c = tid * 4 + i;
    out[ob + i] = (v[i] - mu) * rs * g[c] + b[c];
  }
}

extern "C" void kernel_launch(void* const* d_in, const int* in_sizes, int n_in,
                              void* d_out, int out_size, void* d_ws, size_t ws_size,
                              hipStream_t stream) {
  const float* x    = (const float*)d_in[0];
  const float* Wq   = (const float*)d_in[1];
  const float* bq   = (const float*)d_in[2];
  const float* Wk   = (const float*)d_in[3];
  const float* bk   = (const float*)d_in[4];
  const float* Wv   = (const float*)d_in[5];
  const float* bv   = (const float*)d_in[6];
  const float* demb = (const float*)d_in[7];
  const float* g1   = (const float*)d_in[8];
  const float* b1ln = (const float*)d_in[9];
  const float* g2   = (const float*)d_in[10];
  const float* b2ln = (const float*)d_in[11];
  const float* W1   = (const float*)d_in[12];
  const float* b1   = (const float*)d_in[13];
  const float* W2   = (const float*)d_in[14];
  const float* b2   = (const float*)d_in[15];
  float* outp = (float*)d_out;

  size_t o = 0;
  auto alloc = [&](size_t bytes) { size_t r = o; o += (bytes + 255) & ~(size_t)255; return r; };
  const size_t xb_o    = alloc((size_t)M_ * C_ * 2);
  const size_t wqkv_o  = alloc((size_t)3 * C_ * C_ * 2);   // contiguous with w1,w2
  const size_t w1_o    = alloc((size_t)C_ * C_ * 2);
  const size_t w2_o    = alloc((size_t)C_ * C_ * 2);
  const size_t bqkv_o  = alloc((size_t)3 * C_ * 4);
  const size_t demb_o  = alloc((size_t)DPAD * E_ * 2);
  const size_t q_o     = alloc((size_t)NH_ * L_ * E_ * 2);
  const size_t k_o     = alloc((size_t)NH_ * L_ * E_ * 2);
  const size_t vt_o    = alloc((size_t)NH_ * L_ * E_ * 2);
  const size_t kd_o    = alloc((size_t)NH_ * L_ * D_ * 2);
  const size_t kd0_o   = alloc((size_t)NH_ * L_ * 2);
  const size_t kd256_o = alloc((size_t)NH_ * L_ * 2);
  const size_t t_o     = alloc((size_t)M_ * C_ * 2);
  const size_t h_o     = alloc((size_t)M_ * C_ * 2);
  const size_t m1_o    = alloc((size_t)M_ * C_ * 2);
  const size_t m_o     = alloc((size_t)M_ * C_ * 2);
  if (o > ws_size) return;  // ws too small -> visible zero-output failure

  char* ws = (char*)d_ws;
  u16*   xb     = (u16*)(ws + xb_o);
  u16*   wqkv_t = (u16*)(ws + wqkv_o);
  u16*   w1_t   = (u16*)(ws + w1_o);
  u16*   w2_t   = (u16*)(ws + w2_o);
  float* bqkv   = (float*)(ws + bqkv_o);
  u16*   demb_b = (u16*)(ws + demb_o);
  u16*   q_ws   = (u16*)(ws + q_o);
  u16*   k_ws   = (u16*)(ws + k_o);
  u16*   vT_ws  = (u16*)(ws + vt_o);
  u16*   KD     = (u16*)(ws + kd_o);
  u16*   kd0a   = (u16*)(ws + kd0_o);
  u16*   kd256a = (u16*)(ws + kd256_o);
  u16*   t_b16  = (u16*)(ws + t_o);
  u16*   h_b16  = (u16*)(ws + h_o);
  u16*   m1_b16 = (u16*)(ws + m1_o);
  u16*   m_b16  = (u16*)(ws + m_o);

  prep_kernel<<<4130 + 5120, 256, 0, stream>>>(x, demb, bq, bk, bv,
      Wq, Wk, Wv, W1, W2, xb, demb_b, bqkv, wqkv_t);

  gemm128_kernel<0><<<32 * 24, 256, 0, stream>>>(xb, wqkv_t, C_, bqkv, q_ws, k_ws, vT_ws);

  qdkd_kernel<<<2048, 256, 0, stream>>>(k_ws, demb_b, KD, kd0a, kd256a);

  attn_kernel<<<NH_ * 16, 256, 0, stream>>>(q_ws, k_ws, vT_ws, demb_b, KD, kd0a, kd256a, t_b16);

  ln1_kernel<<<M_, 256, 0, stream>>>(t_b16, x, g1, b1ln, h_b16);

  gemm64_kernel<1><<<64 * 8, 256, 0, stream>>>(h_b16, w1_t, C_, b1, m1_b16);
  gemm64_kernel<2><<<64 * 8, 256, 0, stream>>>(m1_b16, w2_t, C_, b2, m_b16);

  ln2_kernel<<<M_, 256, 0, stream>>>(m_b16, h_b16, g2, b2ln, outp);
}

// Round 14
// 263.285 us; speedup vs baseline: 1.0552x; 1.0552x over previous
//
#include <hip/hip_runtime.h>

#define H_ 32
#define E_ 32
#define C_ 1024
#define L_ 1024
#define N_ 4
#define M_ 4096      // N_*L_
#define NH_ 128      // N_*H_
#define D_ 257
#define DPAD 272     // demb padded rows (zeros beyond 256)
#define QDS 256      // QD row stride in LDS (col 256 lives in a register)
#define TEMP_ 0.17677669529663687f
#define QSCALE_ (TEMP_ * 1.4426950408889634f)   // temp * log2(e), folded into q & KD

typedef unsigned short u16;
typedef __attribute__((ext_vector_type(8))) short short8;
typedef __attribute__((ext_vector_type(4))) float f32x4;
typedef __attribute__((ext_vector_type(4))) unsigned short u16x4;

__device__ __forceinline__ u16 f2bf(float f) {
  union { float f; unsigned u; } v; v.f = f;
  unsigned r = v.u + 0x7fffu + ((v.u >> 16) & 1u);
  return (u16)(r >> 16);
}
__device__ __forceinline__ float bf2f(u16 h) {
  union { unsigned u; float f; } v; v.u = ((unsigned)h) << 16;
  return v.f;
}
__device__ __forceinline__ f32x4 mfma16(short8 a, short8 b, f32x4 c) {
  return __builtin_amdgcn_mfma_f32_16x16x32_bf16(a, b, c, 0, 0, 0);
}
__device__ __forceinline__ float ex2(float x) {
#if __has_builtin(__builtin_amdgcn_exp2f)
  return __builtin_amdgcn_exp2f(x);
#else
  float r;
  asm("v_exp_f32 %0, %1\n\ts_nop 1" : "=v"(r) : "v"(x));
  return r;
#endif
}
// async global->LDS, 16B per lane; lds base must be wave-uniform
__device__ __forceinline__ void gld16(const u16* g, u16* l) {
  __builtin_amdgcn_global_load_lds(
      (const __attribute__((address_space(1))) unsigned int*)g,
      (__attribute__((address_space(3))) unsigned int*)l, 16, 0, 0);
}

// ---- misc: x->bf16 conversion + dist_emb->bf16 (padded) + qkv bias pack ----
__global__ __launch_bounds__(256) void misc_kernel(
    const float* __restrict__ x, const float* __restrict__ demb,
    const float* __restrict__ bq, const float* __restrict__ bk,
    const float* __restrict__ bv, u16* __restrict__ xb,
    u16* __restrict__ demb_b, float* __restrict__ bqkv) {
  const int b = blockIdx.x, tid = threadIdx.x;
  if (b < 4096) {
    int i = b * 256 + tid;
    f32x4 v = reinterpret_cast<const f32x4*>(x)[i];
    u16x4 o2;
    o2[0] = f2bf(v[0]); o2[1] = f2bf(v[1]); o2[2] = f2bf(v[2]); o2[3] = f2bf(v[3]);
    reinterpret_cast<u16x4*>(xb)[i] = o2;
  } else {
    int i = (b - 4096) * 256 + tid;
    if (i < DPAD * E_) demb_b[i] = (i < D_ * E_) ? f2bf(demb[i]) : (u16)0;
    if (i < C_) { bqkv[i] = bq[i]; bqkv[C_ + i] = bk[i]; bqkv[2 * C_ + i] = bv[i]; }
  }
}

// ---- 5 weight transposes in one launch: W (K x N) -> W^T (N x K) bf16 ----
__global__ __launch_bounds__(256) void transpose_w_kernel(
    const float* __restrict__ Wq, const float* __restrict__ Wk,
    const float* __restrict__ Wv, const float* __restrict__ W1,
    const float* __restrict__ W2, u16* __restrict__ out_base) {
  __shared__ float tile[32][33];
  const int z = blockIdx.z;
  const float* in = (z == 0) ? Wq : (z == 1) ? Wk : (z == 2) ? Wv : (z == 3) ? W1 : W2;
  u16* out = out_base + (size_t)z * C_ * C_;
  int j0 = blockIdx.x * 32, c0 = blockIdx.y * 32;
#pragma unroll
  for (int i = 0; i < 4; ++i) {
    int cy = threadIdx.y + i * 8;
    tile[cy][threadIdx.x] = in[(size_t)(c0 + cy) * C_ + j0 + threadIdx.x];
  }
  __syncthreads();
#pragma unroll
  for (int i = 0; i < 4; ++i) {
    int jy = threadIdx.y + i * 8;
    out[(size_t)(j0 + jy) * C_ + c0 + threadIdx.x] = f2bf(tile[threadIdx.x][jy]);
  }
}

// ---- GEMM 128x128: C = A * Bt^T, bf16 in / fp32 acc (qkv projection) ----
template <int EPI>
__global__ __launch_bounds__(256) void gemm128_kernel(
    const u16* __restrict__ A, const u16* __restrict__ Bt, int K,
    const float* __restrict__ bias,
    u16* __restrict__ out0, u16* __restrict__ out1, u16* __restrict__ out2) {
  __shared__ u16 As[128 * 64];
  __shared__ u16 Bs[128 * 64];
  const int bid = blockIdx.x;
  const int m0 = (bid & 31) << 7;
  const int n0 = (bid >> 5) << 7;
  const int tid = threadIdx.x;
  const int w = tid >> 6, lane = tid & 63, lhi = lane >> 4, llo = lane & 15;
  const int wr = w >> 1, wc = w & 1;
  const int w4 = w << 2;
  const int srow = lane >> 3, scol = (lane & 7) << 3;
  f32x4 acc[4][4] = {};
  for (int k0 = 0; k0 < K; k0 += 64) {
#pragma unroll
    for (int j = 0; j < 4; ++j) {
      const int seg = w4 + j;
      const int row = (seg << 3) + srow;
      gld16(&A[(size_t)(m0 + row) * K + k0 + scol], &As[seg << 9]);
      gld16(&Bt[(size_t)(n0 + row) * K + k0 + scol], &Bs[seg << 9]);
    }
    __syncthreads();
#pragma unroll
    for (int kk = 0; kk < 2; ++kk) {
      const int ko = (kk << 5) + lhi * 8;
      short8 af[4], bf[4];
#pragma unroll
      for (int mi = 0; mi < 4; ++mi)
        af[mi] = *reinterpret_cast<const short8*>(&As[(wr * 64 + mi * 16 + llo) * 64 + ko]);
#pragma unroll
      for (int ni = 0; ni < 4; ++ni)
        bf[ni] = *reinterpret_cast<const short8*>(&Bs[(wc * 64 + ni * 16 + llo) * 64 + ko]);
#pragma unroll
      for (int mi = 0; mi < 4; ++mi)
#pragma unroll
        for (int ni = 0; ni < 4; ++ni)
          acc[mi][ni] = mfma16(af[mi], bf[ni], acc[mi][ni]);
    }
    __syncthreads();
  }
#pragma unroll
  for (int mi = 0; mi < 4; ++mi)
#pragma unroll
    for (int ni = 0; ni < 4; ++ni)
#pragma unroll
      for (int r = 0; r < 4; ++r) {
        int row = m0 + wr * 64 + mi * 16 + lhi * 4 + r;
        int col = n0 + wc * 64 + ni * 16 + llo;
        float v = acc[mi][ni][r] + bias[col];
        if constexpr (EPI == 0) {
          int which = col >> 10, jj = col & 1023, h = jj >> 5, e2 = jj & 31;
          int n = row >> 10, l = row & 1023;
          int nh = (n << 5) | h;
          if (which == 0) v *= QSCALE_;   // fold temp*log2e into q
          u16 bvv = f2bf(v);
          if (which == 0)      out0[((size_t)((nh << 10) | l)) * 32 + e2] = bvv;
          else if (which == 1) out1[((size_t)((nh << 10) | l)) * 32 + e2] = bvv;
          else                 out2[(((size_t)(nh * 32 + e2)) << 10) | l] = bvv;
        } else if constexpr (EPI == 1) {
          out0[(size_t)row * C_ + col] = f2bf(fmaxf(v, 0.f));
        } else {
          out0[(size_t)row * C_ + col] = f2bf(v);
        }
      }
}

// ---- GEMM 64x128 (MLP): 512 blocks -> 2 blocks/CU ----
template <int EPI>
__global__ __launch_bounds__(256, 4) void gemm64_kernel(
    const u16* __restrict__ A, const u16* __restrict__ Bt, int K,
    const float* __restrict__ bias, u16* __restrict__ out0) {
  __shared__ u16 As[64 * 64];     // 8192 B
  __shared__ u16 Bs[128 * 64];    // 16384 B
  const int bid = blockIdx.x;
  const int m0 = (bid & 63) << 6;
  const int n0 = (bid >> 6) << 7;
  const int tid = threadIdx.x;
  const int w = tid >> 6, lane = tid & 63, lhi = lane >> 4, llo = lane & 15;
  const int wr = w >> 1, wc = w & 1;   // wr: 32-row half, wc: 64-col half
  const int srow = lane >> 3, scol = (lane & 7) << 3;
  f32x4 acc[2][4] = {};
  for (int k0 = 0; k0 < K; k0 += 64) {
#pragma unroll
    for (int j = 0; j < 2; ++j) {       // A: 8 segs of 8 rows
      const int seg = w * 2 + j;
      const int row = (seg << 3) + srow;
      gld16(&A[(size_t)(m0 + row) * K + k0 + scol], &As[seg << 9]);
    }
#pragma unroll
    for (int j = 0; j < 4; ++j) {       // B: 16 segs of 8 rows
      const int seg = w * 4 + j;
      const int row = (seg << 3) + srow;
      gld16(&Bt[(size_t)(n0 + row) * K + k0 + scol], &Bs[seg << 9]);
    }
    __syncthreads();
#pragma unroll
    for (int kk = 0; kk < 2; ++kk) {
      const int ko = (kk << 5) + lhi * 8;
      short8 af[2], bf[4];
#pragma unroll
      for (int mi = 0; mi < 2; ++mi)
        af[mi] = *reinterpret_cast<const short8*>(&As[(wr * 32 + mi * 16 + llo) * 64 + ko]);
#pragma unroll
      for (int ni = 0; ni < 4; ++ni)
        bf[ni] = *reinterpret_cast<const short8*>(&Bs[(wc * 64 + ni * 16 + llo) * 64 + ko]);
#pragma unroll
      for (int mi = 0; mi < 2; ++mi)
#pragma unroll
        for (int ni = 0; ni < 4; ++ni)
          acc[mi][ni] = mfma16(af[mi], bf[ni], acc[mi][ni]);
    }
    __syncthreads();
  }
#pragma unroll
  for (int mi = 0; mi < 2; ++mi)
#pragma unroll
    for (int ni = 0; ni < 4; ++ni)
#pragma unroll
      for (int r = 0; r < 4; ++r) {
        int row = m0 + wr * 32 + mi * 16 + lhi * 4 + r;
        int col = n0 + wc * 64 + ni * 16 + llo;
        float v = acc[mi][ni][r] + bias[col];
        if constexpr (EPI == 1) out0[(size_t)row * C_ + col] = f2bf(fmaxf(v, 0.f));
        else                    out0[(size_t)row * C_ + col] = f2bf(v);
      }
}

// ---- KD: dst[m, d] = QSCALE * sum_e k[m, e] * demb[d, e]; aux clamp vecs ----
__global__ __launch_bounds__(256) void qdkd_kernel(
    const u16* __restrict__ src, const u16* __restrict__ demb,
    u16* __restrict__ dst, u16* __restrict__ aux0, u16* __restrict__ aux256) {
  const int wt = blockIdx.x * 4 + (threadIdx.x >> 6);
  const int lane = threadIdx.x & 63, lhi = lane >> 4, llo = lane & 15;
  const int m0 = wt << 4;
  short8 a = *reinterpret_cast<const short8*>(&src[(size_t)(m0 + llo) * E_ + lhi * 8]);
#pragma unroll
  for (int ct = 0; ct < 17; ++ct) {
    int d = ct * 16 + llo;
    short8 b = *reinterpret_cast<const short8*>(&demb[d * E_ + lhi * 8]);
    f32x4 c = {};
    c = mfma16(a, b, c);
    if (d < D_) {
#pragma unroll
      for (int r = 0; r < 4; ++r) {
        u16 val = f2bf(c[r] * QSCALE_);
        dst[(size_t)(m0 + lhi * 4 + r) * D_ + d] = val;
        if (d == 0)   aux0[m0 + lhi * 4 + r] = val;
        if (d == 256) aux256[m0 + lhi * 4 + r] = val;
      }
    }
  }
}

// ---- attention (R12 form, 127us floor): x2-unrolled mfma(K,Q) streaming ----
__global__ __launch_bounds__(256, 4) void attn_kernel(
    const u16* __restrict__ qw, const u16* __restrict__ kw,
    const u16* __restrict__ vT, const u16* __restrict__ dembp,
    const u16* __restrict__ KDg, const u16* __restrict__ kd0a,
    const u16* __restrict__ kd256a, u16* __restrict__ tb) {
  __shared__ u16 QDs[64 * QDS];   // 32768 B, wave-local
  __shared__ u16 Pbuf[4 * 1024];  // 8192 B: per-wave 2KB = two 1KB P buffers
  const int bid = blockIdx.x;
  const int nh = bid & (NH_ - 1);     // XCD-friendly
  const int l0 = (bid >> 7) << 6;
  const int tid = threadIdx.x;
  const int w = tid >> 6, lane = tid & 63, lhi = lane >> 4, llo = lane & 15;
  const int lw0 = l0 + (w << 4);
  const int lg = lw0 + llo;
  const int lrow = (w << 4) + llo;    // this lane's q-row within QDs

  const u16* qb  = qw + (size_t)nh * (L_ * E_);
  const u16* kb  = kw + (size_t)nh * (L_ * E_);
  const u16* vb  = vT + (size_t)nh * (E_ * L_);
  const u16* kdg = KDg + (size_t)nh * ((size_t)L_ * D_);
  const u16* k0g = kd0a + (size_t)nh * L_;
  const u16* k2g = kd256a + (size_t)nh * L_;

  const short8 qA = *(const short8*)&qb[(size_t)lg * E_ + lhi * 8];
  const int qr4 = (w << 4) + (lhi << 2);

  char* Pw = reinterpret_cast<char*>(&Pbuf[w * 1024]);   // 2KB region

  // in-kernel QD: rows for this wave only; cols 0..255 in LDS
#pragma unroll
  for (int dt = 0; dt < 16; ++dt) {
    short8 db = *(const short8*)&dembp[(dt * 16 + llo) * E_ + lhi * 8];
    f32x4 qd = {};
    qd = mfma16(qA, db, qd);
#pragma unroll
    for (int r = 0; r < 4; ++r)
      QDs[(qr4 + r) * QDS + dt * 16 + llo] = f2bf(qd[r]);
  }
  // col 256 -> register, via one-time per-wave stash in Pw (overwritten later)
  float qd256;
  {
    short8 db = *(const short8*)&dembp[(size_t)(256 + llo) * E_ + lhi * 8];
    f32x4 qd = {};
    qd = mfma16(qA, db, qd);
    u16* stash = reinterpret_cast<u16*>(Pw);
    if (llo == 0) {
#pragma unroll
      for (int r = 0; r < 4; ++r) stash[(lhi << 2) + r] = f2bf(qd[r]);
    }
    qd256 = bf2f(stash[llo]);   // same-wave LDS, lgkm-ordered
  }
  const float qd0 = bf2f(QDs[lrow * QDS + 0]);

  f32x4 o0 = {}, o1 = {};
  float lacc = 0.f;

#define ASM_SCORE(S0, ST0, ST1, P)                                             \
  {                                                                            \
    const int s0_ = (S0);                                                      \
    const bool far_hi = (lw0 - (s0_ + 31)) >= 128;                             \
    const bool far_lo = (s0_ - (lw0 + 15)) >= 128;                             \
    if (far_hi || far_lo) {                                                    \
      const float qdc = far_hi ? qd256 : qd0;                                  \
      const u16* kcg = far_hi ? k2g : k0g;                                     \
      u16x4 kc0 = *(const u16x4*)&kcg[s0_ + lhi * 4];                          \
      u16x4 kc1 = *(const u16x4*)&kcg[s0_ + 16 + lhi * 4];                     \
      _Pragma("unroll") for (int r = 0; r < 4; ++r) {                          \
        P[r]     = ex2(ST0[r] + qdc + bf2f(kc0[r]));                           \
        P[4 + r] = ex2(ST1[r] + qdc + bf2f(kc1[r]));                           \
      }                                                                        \
    } else {                                                                   \
      _Pragma("unroll") for (int i = 0; i < 2; ++i)                            \
        _Pragma("unroll") for (int r = 0; r < 4; ++r) {                        \
          const int scol = s0_ + i * 16 + lhi * 4 + r;                         \
          int d = lg - scol;                                                   \
          d = (d < -128 ? -128 : (d > 128 ? 128 : d)) + 128;                   \
          int dc = d > 255 ? 255 : d;                                          \
          float qd = (d == 256) ? qd256 : bf2f(QDs[lrow * QDS + dc]);          \
          float kd = bf2f(kdg[(size_t)scol * D_ + d]);                         \
          P[i * 4 + r] = ex2((i ? ST1[r] : ST0[r]) + qd + kd);                 \
        }                                                                      \
    }                                                                          \
  }

#define PACKP(P, OFF)                                                          \
  _Pragma("unroll") for (int i = 0; i < 2; ++i)                                \
    _Pragma("unroll") for (int b = 0; b < 2; ++b) {                            \
      union { float f; unsigned u; } a0_, a1_;                                 \
      a0_.f = P[i * 4 + 2 * b]; a1_.f = P[i * 4 + 2 * b + 1];                  \
      unsigned wv_ = ((a0_.u + 0x8000u) >> 16) | ((a1_.u + 0x8000u) & 0xffff0000u); \
      int u_ = (i * 4 + lhi) ^ (llo & 6);                                      \
      *reinterpret_cast<unsigned*>(Pw + (OFF) + llo * 64 + u_ * 8 + b * 4) = wv_; \
    }

  for (int s0 = 0; s0 < L_; s0 += 64) {
    const int sb = s0 + 32;
    short8 kA0a = *(const short8*)&kb[(size_t)(s0 + llo) * E_ + lhi * 8];
    short8 kA1a = *(const short8*)&kb[(size_t)(s0 + 16 + llo) * E_ + lhi * 8];
    short8 kA0b = *(const short8*)&kb[(size_t)(sb + llo) * E_ + lhi * 8];
    short8 kA1b = *(const short8*)&kb[(size_t)(sb + 16 + llo) * E_ + lhi * 8];
    short8 vA0a = *(const short8*)&vb[(size_t)llo * L_ + s0 + lhi * 8];
    short8 vA1a = *(const short8*)&vb[(size_t)(16 + llo) * L_ + s0 + lhi * 8];
    short8 vA0b = *(const short8*)&vb[(size_t)llo * L_ + sb + lhi * 8];
    short8 vA1b = *(const short8*)&vb[(size_t)(16 + llo) * L_ + sb + lhi * 8];

    f32x4 st0a = {}, st1a = {}, st0b = {}, st1b = {};
    st0a = mfma16(kA0a, qA, st0a);
    st1a = mfma16(kA1a, qA, st1a);
    st0b = mfma16(kA0b, qA, st0b);
    st1b = mfma16(kA1b, qA, st1b);

    float pa[8], pb[8];
    ASM_SCORE(s0, st0a, st1a, pa);
    ASM_SCORE(sb, st0b, st1b, pb);

    lacc += ((pa[0] + pa[1]) + (pa[2] + pa[3])) + ((pa[4] + pa[5]) + (pa[6] + pa[7]));
    lacc += ((pb[0] + pb[1]) + (pb[2] + pb[3])) + ((pb[4] + pb[5]) + (pb[6] + pb[7]));

    PACKP(pa, 0);
    PACKP(pb, 1024);

    short8 pBa = *reinterpret_cast<const short8*>(
        Pw + llo * 64 + (((lhi * 2) ^ (llo & 6)) * 8));
    short8 pBb = *reinterpret_cast<const short8*>(
        Pw + 1024 + llo * 64 + (((lhi * 2) ^ (llo & 6)) * 8));
    o0 = mfma16(vA0a, pBa, o0);
    o1 = mfma16(vA1a, pBa, o1);
    o0 = mfma16(vA0b, pBb, o0);
    o1 = mfma16(vA1b, pBb, o1);
  }
#undef ASM_SCORE
#undef PACKP

  // row sum across the 4 lanes sharing llo (lane, lane^16, lane^32, lane^48)
  float l2 = lacc + __shfl_xor(lacc, 16);
  float lt = l2 + __shfl_xor(l2, 32);
  const float inv = 1.0f / lt;

  const int n = nh >> 5, h = nh & 31;
  const size_t obase = (((size_t)((n << 10) | lg)) * 32 + h) * 32;
  u16x4 w0, w1;
#pragma unroll
  for (int r = 0; r < 4; ++r) {
    w0[r] = f2bf(o0[r] * inv);
    w1[r] = f2bf(o1[r] * inv);
  }
  *reinterpret_cast<u16x4*>(&tb[obase + lhi * 4]) = w0;        // e = lhi*4+r
  *reinterpret_cast<u16x4*>(&tb[obase + 16 + lhi * 4]) = w1;   // e = 16+lhi*4+r
}

// ---- AddNorm 1: h = LN(t + x) -> bf16 ----
__global__ __launch_bounds__(256) void ln1_kernel(
    const u16* __restrict__ tbuf, const float* __restrict__ x,
    const float* __restrict__ g, const float* __restrict__ b,
    u16* __restrict__ hb) {
  __shared__ float red[8];
  const int row = blockIdx.x, tid = threadIdx.x;
  const size_t base = (size_t)row * C_ + tid * 4;
  f32x4 xv = *reinterpret_cast<const f32x4*>(&x[base]);
  u16x4 tv = *reinterpret_cast<const u16x4*>(&tbuf[base]);
  float v[4]; float s1 = 0.f, s2 = 0.f;
#pragma unroll
  for (int i = 0; i < 4; ++i) {
    v[i] = xv[i] + bf2f(tv[i]);
    s1 += v[i]; s2 += v[i] * v[i];
  }
#pragma unroll
  for (int off = 32; off >= 1; off >>= 1) {
    s1 += __shfl_xor(s1, off); s2 += __shfl_xor(s2, off);
  }
  if ((tid & 63) == 0) { red[tid >> 6] = s1; red[4 + (tid >> 6)] = s2; }
  __syncthreads();
  float S1 = red[0] + red[1] + red[2] + red[3];
  float S2 = red[4] + red[5] + red[6] + red[7];
  float mu = S1 * (1.f / C_);
  float rs = rsqrtf(S2 * (1.f / C_) - mu * mu + 1e-5f);
#pragma unroll
  for (int i = 0; i < 4; ++i) {
    int c = tid * 4 + i;
    hb[base + i] = f2bf((v[i] - mu) * rs * g[c] + b[c]);
  }
}

// ---- AddNorm 2: out = LN(m + h) -> fp32, transposed (L, N, C) ----
__global__ __launch_bounds__(256) void ln2_kernel(
    const u16* __restrict__ mb, const u16* __restrict__ hb,
    const float* __restrict__ g, const float* __restrict__ b,
    float* __restrict__ out) {
  __shared__ float red[8];
  const int row = blockIdx.x, tid = threadIdx.x;
  const size_t base = (size_t)row * C_ + tid * 4;
  u16x4 mv = *reinterpret_cast<const u16x4*>(&mb[base]);
  u16x4 hv = *reinterpret_cast<const u16x4*>(&hb[base]);
  float v[4]; float s1 = 0.f, s2 = 0.f;
#pragma unroll
  for (int i = 0; i < 4; ++i) {
    v[i] = bf2f(mv[i]) + bf2f(hv[i]);
    s1 += v[i]; s2 += v[i] * v[i];
  }
#pragma unroll
  for (int off = 32; off >= 1; off >>= 1) {
    s1 += __shfl_xor(s1, off); s2 += __shfl_xor(s2, off);
  }
  if ((tid & 63) == 0) { red[tid >> 6] = s1; red[4 + (tid >> 6)] = s2; }
  __syncthreads();
  float S1 = red[0] + red[1] + red[2] + red[3];
  float S2 = red[4] + red[5] + red[6] + red[7];
  float mu = S1 * (1.f / C_);
  float rs = rsqrtf(S2 * (1.f / C_) - mu * mu + 1e-5f);
  const int n = row >> 10, l = row & 1023;
  const size_t ob = (size_t)(l * N_ + n) * C_ + tid * 4;
#pragma unroll
  for (int i = 0; i < 4; ++i) {
    int c = tid * 4 + i;
    out[ob + i] = (v[i] - mu) * rs * g[c] + b[c];
  }
}

extern "C" void kernel_launch(void* const* d_in, const int* in_sizes, int n_in,
                              void* d_out, int out_size, void* d_ws, size_t ws_size,
                              hipStream_t stream) {
  const float* x    = (const float*)d_in[0];
  const float* Wq   = (const float*)d_in[1];
  const float* bq   = (const float*)d_in[2];
  const float* Wk   = (const float*)d_in[3];
  const float* bk   = (const float*)d_in[4];
  const float* Wv   = (const float*)d_in[5];
  const float* bv   = (const float*)d_in[6];
  const float* demb = (const float*)d_in[7];
  const float* g1   = (const float*)d_in[8];
  const float* b1ln = (const float*)d_in[9];
  const float* g2   = (const float*)d_in[10];
  const float* b2ln = (const float*)d_in[11];
  const float* W1   = (const float*)d_in[12];
  const float* b1   = (const float*)d_in[13];
  const float* W2   = (const float*)d_in[14];
  const float* b2   = (const float*)d_in[15];
  float* outp = (float*)d_out;

  size_t o = 0;
  auto alloc = [&](size_t bytes) { size_t r = o; o += (bytes + 255) & ~(size_t)255; return r; };
  const size_t xb_o    = alloc((size_t)M_ * C_ * 2);
  const size_t wqkv_o  = alloc((size_t)3 * C_ * C_ * 2);   // contiguous with w1,w2
  const size_t w1_o    = alloc((size_t)C_ * C_ * 2);
  const size_t w2_o    = alloc((size_t)C_ * C_ * 2);
  const size_t bqkv_o  = alloc((size_t)3 * C_ * 4);
  const size_t demb_o  = alloc((size_t)DPAD * E_ * 2);
  const size_t q_o     = alloc((size_t)NH_ * L_ * E_ * 2);
  const size_t k_o     = alloc((size_t)NH_ * L_ * E_ * 2);
  const size_t vt_o    = alloc((size_t)NH_ * L_ * E_ * 2);
  const size_t kd_o    = alloc((size_t)NH_ * L_ * D_ * 2);
  const size_t kd0_o   = alloc((size_t)NH_ * L_ * 2);
  const size_t kd256_o = alloc((size_t)NH_ * L_ * 2);
  const size_t t_o     = alloc((size_t)M_ * C_ * 2);
  const size_t h_o     = alloc((size_t)M_ * C_ * 2);
  const size_t m1_o    = alloc((size_t)M_ * C_ * 2);
  const size_t m_o     = alloc((size_t)M_ * C_ * 2);
  if (o > ws_size) return;  // ws too small -> visible zero-output failure

  char* ws = (char*)d_ws;
  u16*   xb     = (u16*)(ws + xb_o);
  u16*   wqkv_t = (u16*)(ws + wqkv_o);
  u16*   w1_t   = (u16*)(ws + w1_o);
  u16*   w2_t   = (u16*)(ws + w2_o);
  float* bqkv   = (float*)(ws + bqkv_o);
  u16*   demb_b = (u16*)(ws + demb_o);
  u16*   q_ws   = (u16*)(ws + q_o);
  u16*   k_ws   = (u16*)(ws + k_o);
  u16*   vT_ws  = (u16*)(ws + vt_o);
  u16*   KD     = (u16*)(ws + kd_o);
  u16*   kd0a   = (u16*)(ws + kd0_o);
  u16*   kd256a = (u16*)(ws + kd256_o);
  u16*   t_b16  = (u16*)(ws + t_o);
  u16*   h_b16  = (u16*)(ws + h_o);
  u16*   m1_b16 = (u16*)(ws + m1_o);
  u16*   m_b16  = (u16*)(ws + m_o);

  misc_kernel<<<4096 + 34, 256, 0, stream>>>(x, demb, bq, bk, bv, xb, demb_b, bqkv);
  dim3 tb_(32, 8), tg_(32, 32, 5);
  transpose_w_kernel<<<tg_, tb_, 0, stream>>>(Wq, Wk, Wv, W1, W2, wqkv_t);

  gemm128_kernel<0><<<32 * 24, 256, 0, stream>>>(xb, wqkv_t, C_, bqkv, q_ws, k_ws, vT_ws);

  qdkd_kernel<<<2048, 256, 0, stream>>>(k_ws, demb_b, KD, kd0a, kd256a);

  attn_kernel<<<NH_ * 16, 256, 0, stream>>>(q_ws, k_ws, vT_ws, demb_b, KD, kd0a, kd256a, t_b16);

  ln1_kernel<<<M_, 256, 0, stream>>>(t_b16, x, g1, b1ln, h_b16);

  gemm64_kernel<1><<<64 * 8, 256, 0, stream>>>(h_b16, w1_t, C_, b1, m1_b16);
  gemm64_kernel<2><<<64 * 8, 256, 0, stream>>>(m1_b16, w2_t, C_, b2, m_b16);

  ln2_kernel<<<M_, 256, 0, stream>>>(m_b16, h_b16, g2, b2ln, outp);
}